// Round 7
// baseline (133.690 us; speedup 1.0000x reference)
//
#include <hip/hip_runtime.h>
#include <hip/hip_bf16.h>
#include <stdint.h>

// out = x @ W^T + bias; W[f,n] = sum_k scale[k,f]*(bit(7-n%8) of binary[k,f,n/8] ? +1 : -1)
// Round 7: coarse-phase GEMM. 128x256 tile, 4 waves (wave-tile 128x64),
// grid 512 = 2 independent blocks/CU (stochastic DS/MFMA overlap + tail hiding).
// LDS 80KB: A single-buf 16KB + B double-buf 2x32KB. ONE barrier-pair per
// K-tile (32 MFMA per barrier). ds_reads are compiler-scheduled (auto counted
// lgkm waits); manual waits only for gload_lds->LDS (vmcnt) and the A-restage
// fence (lgkm0+barrier). T1 XCD swizzle + T2 XOR swizzle + T5 setprio kept.

#define BITS 8
#define NF   4096
#define NXX  1024
#define GRP  (NXX / 8)

#define BM 128
#define BN 256
#define BK 64

typedef __attribute__((ext_vector_type(4))) float f32x4;
typedef __attribute__((ext_vector_type(8))) short bf16x8;

// ---------------- prep: cast x (blocks 0..2047) + decode W (blocks 2048..4095) ----
__global__ __launch_bounds__(256) void k_prep(const float* __restrict__ x,
                                              const int* __restrict__ binary,
                                              const float* __restrict__ scale,
                                              __hip_bfloat16* __restrict__ xb,
                                              __hip_bfloat16* __restrict__ Wb) {
    const int b = blockIdx.x;
    const int tid = threadIdx.x;
    if (b < 2048) {
        int i = b * 256 + tid;
        const float4* xp = (const float4*)x;
        float4 a = xp[2 * i], c = xp[2 * i + 1];
        union { __hip_bfloat16 h[8]; int4 v; } u;
        u.h[0] = __float2bfloat16(a.x);
        u.h[1] = __float2bfloat16(a.y);
        u.h[2] = __float2bfloat16(a.z);
        u.h[3] = __float2bfloat16(a.w);
        u.h[4] = __float2bfloat16(c.x);
        u.h[5] = __float2bfloat16(c.y);
        u.h[6] = __float2bfloat16(c.z);
        u.h[7] = __float2bfloat16(c.w);
        ((int4*)xb)[i] = u.v;
    } else {
        int idx = (b - 2048) * 256 + tid;       // 0 .. NF*GRP-1
        int f = idx >> 7;                       // GRP = 128
        int g = idx & (GRP - 1);
        float sc[BITS];
        int   bv[BITS];
#pragma unroll
        for (int k = 0; k < BITS; ++k) {
            sc[k] = scale[k * NF + f];
            bv[k] = binary[(size_t)(k * NF + f) * GRP + g];
        }
        union { __hip_bfloat16 h[8]; int4 v; } u;
#pragma unroll
        for (int j = 0; j < 8; ++j) {           // element j uses bit (7-j)
            float s = 0.f;
#pragma unroll
            for (int k = 0; k < BITS; ++k)
                s += ((bv[k] >> (7 - j)) & 1) ? sc[k] : -sc[k];
            u.h[j] = __float2bfloat16(s);
        }
        ((int4*)Wb)[idx] = u.v;
    }
}

// ---------------- GEMM: C[M,N] = A[M,K] * B[N,K]^T + bias ----------------
__global__ __launch_bounds__(256, 2) void k_gemm(const __hip_bfloat16* __restrict__ A,
                                                 const __hip_bfloat16* __restrict__ B,
                                                 const float* __restrict__ bias,
                                                 float* __restrict__ C,
                                                 int M, int N, int K) {
    // LDS: A [128 rows][128B] @0 (16KB); B bufs @16384 + b*32768 ([256][128B])
    __shared__ __align__(16) char lds[81920];

    const int tid  = threadIdx.x;
    const int lane = tid & 63;
    const int wv   = tid >> 6;      // 0..3
    const int lr = lane & 15;       // fragment row/col
    const int lk = lane >> 4;       // K-octet 0..3

    // T1: XCD swizzle. grid=512 -> 64 blocks/XCD, m fast-varying within XCD.
    const int bid = blockIdx.x;
    const int swz = (bid & 7) * 64 + (bid >> 3);
    const int m0 = (swz & 31) * BM;
    const int n0 = (swz >> 5) * BN;

    const int NT = K / BK;          // 16

    // staging constants (T2: source chunk pre-swizzled, LDS dest linear)
    int offA[4], offB[8];
#pragma unroll
    for (int j = 0; j < 4; ++j) {
        int c = j * 256 + tid, r = c >> 3, q = c & 7;
        offA[j] = r * K + (q ^ (r & 7)) * 8;
    }
#pragma unroll
    for (int j = 0; j < 8; ++j) {
        int c = j * 256 + tid, r = c >> 3, q = c & 7;
        offB[j] = r * K + (q ^ (r & 7)) * 8;
    }
    const __hip_bfloat16* Abase = A + (size_t)m0 * K;
    const __hip_bfloat16* Bbase = B + (size_t)n0 * K;

    auto stageA = [&](int kt) {
#pragma unroll
        for (int j = 0; j < 4; ++j)
            __builtin_amdgcn_global_load_lds(
                (const __attribute__((address_space(1))) void*)(Abase + offA[j] + kt),
                (__attribute__((address_space(3))) void*)(lds + (j * 256 + tid) * 16), 16, 0, 0);
    };
    auto stageB = [&](int buf, int kt) {
#pragma unroll
        for (int j = 0; j < 8; ++j)
            __builtin_amdgcn_global_load_lds(
                (const __attribute__((address_space(1))) void*)(Bbase + offB[j] + kt),
                (__attribute__((address_space(3))) void*)(lds + 16384 + buf * 32768 + (j * 256 + tid) * 16), 16, 0, 0);
    };
    // swizzled LDS reads: logical (row R, col-byte CB) -> CB ^ ((R&7)<<4)
    auto ldA = [&](int i, int kk) -> bf16x8 {
        int R = i * 16 + lr;
        int CB = (kk * 64 + lk * 16) ^ ((R & 7) << 4);
        return *(const bf16x8*)(lds + R * 128 + CB);
    };
    auto ldB = [&](int buf, int j, int kk) -> bf16x8 {
        int R = wv * 64 + j * 16 + lr;
        int CB = (kk * 64 + lk * 16) ^ ((R & 7) << 4);
        return *(const bf16x8*)(lds + 16384 + buf * 32768 + R * 128 + CB);
    };

    f32x4 acc[8][4] = {};
    bf16x8 aF[4][2], aG[4][2], bF[4][2];

    // prologue: tile 0
    stageA(0);
    stageB(0, 0);

    for (int t = 0; t < NT; ++t) {
        const int cb = t & 1;
        const bool st = (t + 1 < NT);
        // A(t)/B(t) arrived (issued a full tile ago in steady state; L2-resident)
        asm volatile("s_waitcnt vmcnt(0)" ::: "memory");
        __builtin_amdgcn_s_barrier();

        // stage next B into the idle buffer (its readers retired at t-1 mid-fence)
        if (st) stageB(cb ^ 1, (t + 1) * BK);

        // all fragment reads for this tile; compiler interleaves + counted-waits
#pragma unroll
        for (int i = 0; i < 4; ++i) { aF[i][0] = ldA(i, 0); aF[i][1] = ldA(i, 1); }
#pragma unroll
        for (int j = 0; j < 4; ++j) { bF[j][0] = ldB(cb, j, 0); bF[j][1] = ldB(cb, j, 1); }
#pragma unroll
        for (int i = 0; i < 4; ++i) { aG[i][0] = ldA(4 + i, 0); aG[i][1] = ldA(4 + i, 1); }

        // MFMA half 0 (m 0..63): 32 MFMAs
        __builtin_amdgcn_s_setprio(1);
#pragma unroll
        for (int i = 0; i < 4; ++i)
#pragma unroll
            for (int j = 0; j < 4; ++j)
#pragma unroll
                for (int kk = 0; kk < 2; ++kk)
                    acc[i][j] = __builtin_amdgcn_mfma_f32_16x16x32_bf16(
                        aF[i][kk], bF[j][kk], acc[i][j], 0, 0, 0);
        __builtin_amdgcn_s_setprio(0);

        // all waves' A-reads (aF+aG) retired -> safe to overwrite A region
        asm volatile("s_waitcnt lgkmcnt(0)" ::: "memory");
        __builtin_amdgcn_s_barrier();
        if (st) stageA((t + 1) * BK);   // latency hidden under MFMA half 1

        // MFMA half 1 (m 64..127): 32 MFMAs
        __builtin_amdgcn_s_setprio(1);
#pragma unroll
        for (int i = 0; i < 4; ++i)
#pragma unroll
            for (int j = 0; j < 4; ++j)
#pragma unroll
                for (int kk = 0; kk < 2; ++kk)
                    acc[4 + i][j] = __builtin_amdgcn_mfma_f32_16x16x32_bf16(
                        aG[i][kk], bF[j][kk], acc[4 + i][j], 0, 0, 0);
        __builtin_amdgcn_s_setprio(0);
    }

    // epilogue: C/D layout col = lane&15, row = (lane>>4)*4 + r
#pragma unroll
    for (int j = 0; j < 4; ++j) {
        int col = n0 + wv * 64 + j * 16 + lr;
        float bv = bias[col];
#pragma unroll
        for (int i = 0; i < 8; ++i) {
            int row = m0 + i * 16 + lk * 4;
#pragma unroll
            for (int r = 0; r < 4; ++r)
                C[(size_t)(row + r) * N + col] = acc[i][j][r] + bv;
        }
    }
}

extern "C" void kernel_launch(void* const* d_in, const int* in_sizes, int n_in,
                              void* d_out, int out_size, void* d_ws, size_t ws_size,
                              hipStream_t stream) {
    const float* x      = (const float*)d_in[0];
    const int*   binary = (const int*)d_in[1];
    const float* scale  = (const float*)d_in[2];
    const float* bias   = (const float*)d_in[3];
    float* out = (float*)d_out;

    const int M = in_sizes[0] / NXX;   // 4096 tokens

    __hip_bfloat16* xb = (__hip_bfloat16*)d_ws;                 // 8 MB
    __hip_bfloat16* Wb = xb + (size_t)M * NXX;                  // 8 MB

    k_prep<<<2048 + (NF * GRP) / 256, 256, 0, stream>>>(x, binary, scale, xb, Wb);
    k_gemm<<<(M / BM) * (NF / BN), 256, 0, stream>>>(xb, Wb, bias, out, M, NF, NXX);
}